// Round 6
// baseline (322.955 us; speedup 1.0000x reference)
//
#include <hip/hip_runtime.h>
#include <cmath>

#define NPIX 16384
#define NATOM 1024
#define DIM 64
#define SPAR 8

// ---------------------------------------------------------------------------
// Pre-pass: block k1 computes G row k1 = (D^T D + 1e-4 I)[k1,:] (fp64 acc),
// the Dt row (transpose for the recon gather), and Gd[k1] = G[k1][k1].
// ---------------------------------------------------------------------------
__global__ __launch_bounds__(256) void k_pre(const float* __restrict__ D,
                                             float* __restrict__ G,
                                             float* __restrict__ Dt,
                                             float* __restrict__ Gd) {
  const int k1 = blockIdx.x;
  __shared__ float d1[DIM];
  if (threadIdx.x < DIM) {
    float v = D[(size_t)threadIdx.x * NATOM + k1];
    d1[threadIdx.x] = v;
    Dt[(size_t)k1 * DIM + threadIdx.x] = v;
  }
  __syncthreads();
  for (int k2 = threadIdx.x; k2 < NATOM; k2 += 256) {
    double acc = 0.0;
#pragma unroll
    for (int d = 0; d < DIM; ++d)
      acc += (double)d1[d] * (double)D[(size_t)d * NATOM + k2];
    float g = (float)acc;
    if (k2 == k1) {
      g += 1e-4f;
      Gd[k1] = g;
    }
    G[(size_t)k1 * NATOM + k2] = g;
  }
}

// ---------------------------------------------------------------------------
// DPP wave64 reductions (VALU latency, no LDS): row_shr 1/2/4/8 then
// row_bcast15/31 leaves the full reduce in lane 63; readlane broadcasts.
// old = x with bound_ctrl=false -> invalid lanes keep x (neutral element).
// ---------------------------------------------------------------------------
template <int CTRL>
__device__ __forceinline__ float dpp_fmax(float x) {
  int s = __builtin_amdgcn_update_dpp(__float_as_int(x), __float_as_int(x),
                                      CTRL, 0xf, 0xf, false);
  return fmaxf(x, __int_as_float(s));
}
template <int CTRL>
__device__ __forceinline__ unsigned dpp_umin(unsigned x) {
  unsigned s = (unsigned)__builtin_amdgcn_update_dpp((int)x, (int)x, CTRL,
                                                     0xf, 0xf, false);
  return x < s ? x : s;
}
__device__ __forceinline__ float wave_max_bcast(float x) {
  x = dpp_fmax<0x111>(x);  // row_shr:1
  x = dpp_fmax<0x112>(x);  // row_shr:2
  x = dpp_fmax<0x114>(x);  // row_shr:4
  x = dpp_fmax<0x118>(x);  // row_shr:8
  x = dpp_fmax<0x142>(x);  // row_bcast:15
  x = dpp_fmax<0x143>(x);  // row_bcast:31
  return __int_as_float(__builtin_amdgcn_readlane(__float_as_int(x), 63));
}
__device__ __forceinline__ int wave_minu_bcast(unsigned x) {
  x = dpp_umin<0x111>(x);
  x = dpp_umin<0x112>(x);
  x = dpp_umin<0x114>(x);
  x = dpp_umin<0x118>(x);
  x = dpp_umin<0x142>(x);
  x = dpp_umin<0x143>(x);
  return __builtin_amdgcn_readlane((int)x, 63);
}

// ---------------------------------------------------------------------------
// Batched OMP: one 64-lane wave per pixel. Lane owns k = lane*16+j, j=0..15.
// h_bar is computed in-kernel (ascending-d fp32 fmaf — bitwise identical to
// the previous staged GEMM). Argmax: exact f32 wave max via DPP, then
// wave-min index among score==M (first occurrence == np.argmax). Selected
// G rows pinned in registers; diag from LDS-staged Gd.
// ---------------------------------------------------------------------------
template <bool DTW>
__global__ __launch_bounds__(256, 2) void k_omp(const float* __restrict__ X,
                                                const float* __restrict__ D,
                                                const float* __restrict__ Dt,
                                                const float* __restrict__ G,
                                                const float* __restrict__ Gd,
                                                float* __restrict__ out) {
  const int lane = threadIdx.x & 63;
  const int lane16 = lane * 16;
  const int n =
      __builtin_amdgcn_readfirstlane(blockIdx.x * 4 + (threadIdx.x >> 6));

  // stage G diagonal (4 KB) into LDS once
  __shared__ float gdiag[NATOM];
  for (int i = threadIdx.x; i < NATOM; i += 256) gdiag[i] = Gd[i];
  __syncthreads();

  // ---- hb[j] = sum_d X[d][n] * D[d][lane16+j], fp32 ascending d ----
  float hb[16];
#pragma unroll
  for (int j = 0; j < 16; ++j) hb[j] = 0.f;
#pragma unroll 8
  for (int d = 0; d < DIM; ++d) {
    const float xd = X[(size_t)d * NPIX + n];  // wave-uniform scalar load
    const float* dr = D + (size_t)d * NATOM + lane16;
    float4 a = *reinterpret_cast<const float4*>(dr);
    float4 b = *reinterpret_cast<const float4*>(dr + 4);
    float4 c = *reinterpret_cast<const float4*>(dr + 8);
    float4 e = *reinterpret_cast<const float4*>(dr + 12);
    hb[0] = fmaf(xd, a.x, hb[0]);  hb[1] = fmaf(xd, a.y, hb[1]);
    hb[2] = fmaf(xd, a.z, hb[2]);  hb[3] = fmaf(xd, a.w, hb[3]);
    hb[4] = fmaf(xd, b.x, hb[4]);  hb[5] = fmaf(xd, b.y, hb[5]);
    hb[6] = fmaf(xd, b.z, hb[6]);  hb[7] = fmaf(xd, b.w, hb[7]);
    hb[8] = fmaf(xd, c.x, hb[8]);  hb[9] = fmaf(xd, c.y, hb[9]);
    hb[10] = fmaf(xd, c.z, hb[10]); hb[11] = fmaf(xd, c.w, hb[11]);
    hb[12] = fmaf(xd, e.x, hb[12]); hb[13] = fmaf(xd, e.y, hb[13]);
    hb[14] = fmaf(xd, e.z, hb[14]); hb[15] = fmaf(xd, e.w, hb[15]);
  }
#pragma unroll
  for (int j = 0; j < 16; ++j) asm volatile("" : "+v"(hb[j]));

  unsigned mask = 0;  // bit j: atom (lane16+j) already selected
  int selI[SPAR];
  float rows[SPAR - 1][16];  // rows[i][j] = G[selI[i]][lane16+j]
  float Lm[SPAR][SPAR], invL[SPAR], ysel[SPAR], coefF[SPAR];

#pragma unroll 8
  for (int s = 0; s < SPAR; ++s) {
    // ---- scores ----
    float sc[16];
#pragma unroll
    for (int j = 0; j < 16; ++j) {
      float h = hb[j];
#pragma unroll
      for (int i = 0; i < SPAR - 1; ++i)
        if (i < s) h = fmaf(-coefF[i], rows[i][j], h);
      sc[j] = ((mask >> j) & 1u) ? -1.0f : fabsf(h);
    }
    // ---- wave max (exact f32, DPP) ----
    float m0 = fmaxf(fmaxf(fmaxf(sc[0], sc[1]), sc[2]), sc[3]);
    float m1 = fmaxf(fmaxf(fmaxf(sc[4], sc[5]), sc[6]), sc[7]);
    float m2 = fmaxf(fmaxf(fmaxf(sc[8], sc[9]), sc[10]), sc[11]);
    float m3 = fmaxf(fmaxf(fmaxf(sc[12], sc[13]), sc[14]), sc[15]);
    const float M = wave_max_bcast(fmaxf(fmaxf(m0, m1), fmaxf(m2, m3)));
    // ---- min index among score==M (first occurrence, as np.argmax) ----
    unsigned sel = NATOM;
#pragma unroll
    for (int j = 0; j < 16; ++j) {
      unsigned idx = (unsigned)(lane16 + j);
      unsigned cand = (sc[j] == M) ? idx : (unsigned)NATOM;
      sel = sel < cand ? sel : cand;
    }
    const int bk = wave_minu_bcast(sel);  // SGPR, wave-uniform
    selI[s] = bk;
    const int bl = bk >> 4, bj = bk & 15;
    if (lane == bl) mask |= (1u << bj);

    // gather h_bar[bk] (compile-time-indexed select + shfl)
    float v = 0.f;
#pragma unroll
    for (int j = 0; j < 16; ++j)
      if (j == bj) v = hb[j];
    const float hbs = __shfl(v, bl);

    // issue new-row fetch (dwordx4 x4); completes during chol/solve below
    if (s < SPAR - 1) {
#pragma unroll
      for (int q = 0; q < 4; ++q) {
        float4 rv = *reinterpret_cast<const float4*>(
            &G[(size_t)bk * NATOM + lane16 + q * 4]);
        rows[s][q * 4 + 0] = rv.x; rows[s][q * 4 + 1] = rv.y;
        rows[s][q * 4 + 2] = rv.z; rows[s][q * 4 + 3] = rv.w;
      }
    }

    // ---- Cholesky update: L_{s+1} = [[L, 0], [w^T, corner]] ----
    const float diag = gdiag[bk];  // uniform LDS broadcast
    float w[SPAR];
    float sq = 0.f;
#pragma unroll
    for (int i = 0; i < SPAR; ++i)
      if (i < s) {
        float a = G[(size_t)selI[i] * NATOM + bk];  // uniform (scalar) load
#pragma unroll
        for (int t = 0; t < SPAR; ++t)
          if (t < i) a = fmaf(-Lm[i][t], w[t], a);
        w[i] = a * invL[i];
        sq += w[i] * w[i];
        Lm[s][i] = w[i];
      }
    float cc = diag - sq;
    if (cc < 1e-6f) cc = 1e-6f;  // jnp.clip(..., CHOL_EPS)
    Lm[s][s] = sqrtf(cc);
    invL[s] = 1.0f / Lm[s][s];

    // ---- y_s (incremental forward solve) ----
    {
      float a = hbs;
#pragma unroll
      for (int t = 0; t < SPAR; ++t)
        if (t < s) a = fmaf(-Lm[s][t], ysel[t], a);
      ysel[s] = a * invL[s];
    }
    // ---- coef: backward solve L^T x = y ----
#pragma unroll
    for (int i = SPAR - 1; i >= 0; --i)
      if (i <= s) {
        float a = ysel[i];
#pragma unroll
        for (int t = 0; t < SPAR; ++t)
          if (t > i && t <= s) a = fmaf(-Lm[t][i], coefF[t], a);
        coefF[i] = a * invL[i];
      }

    // pin the fetched row: forces residency; waitcnt lands here (post-solve)
    if (s < SPAR - 1) {
#pragma unroll
      for (int j = 0; j < 16; ++j) asm volatile("" : "+v"(rows[s][j]));
    }
  }

  // ---- outputs: recon [n][64], I [n][8], coeffs [n][8] ----
  double r = 0.0;
#pragma unroll
  for (int i = 0; i < SPAR; ++i) {
    float dv = DTW ? Dt[(size_t)selI[i] * DIM + lane]
                   : D[(size_t)lane * NATOM + selI[i]];
    r += (double)coefF[i] * (double)dv;
  }
  out[(size_t)n * DIM + lane] = (float)r;

  float fi = 0.f, fc = 0.f;
#pragma unroll
  for (int i = 0; i < SPAR; ++i)
    if (lane == i) { fi = (float)selI[i]; fc = coefF[i]; }
  if (lane < SPAR) {
    out[(size_t)NPIX * DIM + (size_t)n * SPAR + lane] = fi;
    out[(size_t)NPIX * DIM + (size_t)NPIX * SPAR + (size_t)n * SPAR + lane] = fc;
  }
}

extern "C" void kernel_launch(void* const* d_in, const int* in_sizes, int n_in,
                              void* d_out, int out_size, void* d_ws,
                              size_t ws_size, hipStream_t stream) {
  const float* X = (const float*)d_in[0];  // [64, 16384]
  const float* D = (const float*)d_in[1];  // [64, 1024]
  float* out = (float*)d_out;              // [recon | I | coeffs] as fp32
  float* G = (float*)d_ws;                 // 4 MB
  float* Dt = G + (size_t)NATOM * NATOM;   // 256 KB
  float* Gd = Dt + (size_t)NATOM * DIM;    // 4 KB
  const size_t need =
      ((size_t)NATOM * NATOM + (size_t)NATOM * DIM + NATOM) * sizeof(float);

  k_pre<<<dim3(NATOM), dim3(256), 0, stream>>>(D, G, Dt, Gd);
  if (ws_size >= need) {
    k_omp<true><<<dim3(NPIX / 4), dim3(256), 0, stream>>>(X, D, Dt, G, Gd, out);
  } else {
    k_omp<false><<<dim3(NPIX / 4), dim3(256), 0, stream>>>(X, D, nullptr, G, Gd, out);
  }
}

// Round 7
// 134.705 us; speedup vs baseline: 2.3975x; 2.3975x over previous
//
#include <hip/hip_runtime.h>
#include <cmath>

#define NPIX 16384
#define NATOM 1024
#define DIM 64
#define SPAR 8

// ---------------------------------------------------------------------------
// Fused pre-pass, grid-partitioned:
//   blocks [0, 1024):    G row k1 = D^T D + 1e-4 I (fp64 acc); Dt row; Gd[k1]
//   blocks [1024, 2048): HB 128n x 128k tile (fp32, 8x8/thread)
// ---------------------------------------------------------------------------
__global__ __launch_bounds__(256) void k_pre(const float* __restrict__ X,
                                             const float* __restrict__ D,
                                             float* __restrict__ G,
                                             float* __restrict__ Dt,
                                             float* __restrict__ Gd,
                                             float* __restrict__ HB) {
  __shared__ float smem[2 * DIM * 128];  // 64 KiB
  if (blockIdx.x < NATOM) {
    const int k1 = blockIdx.x;
    float* d1 = smem;
    if (threadIdx.x < DIM) {
      float v = D[(size_t)threadIdx.x * NATOM + k1];
      d1[threadIdx.x] = v;
      Dt[(size_t)k1 * DIM + threadIdx.x] = v;  // transpose for recon gather
    }
    __syncthreads();
    for (int k2 = threadIdx.x; k2 < NATOM; k2 += 256) {
      double acc = 0.0;
#pragma unroll
      for (int d = 0; d < DIM; ++d)
        acc += (double)d1[d] * (double)D[(size_t)d * NATOM + k2];
      float g = (float)acc;
      if (k2 == k1) {
        g += 1e-4f;
        Gd[k1] = g;
      }
      G[(size_t)k1 * NATOM + k2] = g;
    }
  } else {
    const int bx = blockIdx.x - NATOM;
    const int n0 = (bx & 127) * 128, k0 = (bx >> 7) * 128;
    float(*sX)[128] = (float(*)[128])smem;
    float(*sD)[128] = (float(*)[128])(smem + DIM * 128);
    for (int i = threadIdx.x; i < DIM * 32; i += 256) {
      int d = i >> 5, c4 = (i & 31) * 4;
      *reinterpret_cast<float4*>(&sX[d][c4]) =
          *reinterpret_cast<const float4*>(&X[(size_t)d * NPIX + n0 + c4]);
      *reinterpret_cast<float4*>(&sD[d][c4]) =
          *reinterpret_cast<const float4*>(&D[(size_t)d * NATOM + k0 + c4]);
    }
    __syncthreads();
    const int nl = (threadIdx.x & 15) * 8;
    const int kl = (threadIdx.x >> 4) * 8;
    float acc[8][8];
#pragma unroll
    for (int i = 0; i < 8; ++i)
#pragma unroll
      for (int j = 0; j < 8; ++j) acc[i][j] = 0.f;
#pragma unroll 4
    for (int d = 0; d < DIM; ++d) {
      float xv[8], dv[8];
      *reinterpret_cast<float4*>(&xv[0]) = *reinterpret_cast<float4*>(&sX[d][nl]);
      *reinterpret_cast<float4*>(&xv[4]) = *reinterpret_cast<float4*>(&sX[d][nl + 4]);
      *reinterpret_cast<float4*>(&dv[0]) = *reinterpret_cast<float4*>(&sD[d][kl]);
      *reinterpret_cast<float4*>(&dv[4]) = *reinterpret_cast<float4*>(&sD[d][kl + 4]);
#pragma unroll
      for (int i = 0; i < 8; ++i)
#pragma unroll
        for (int j = 0; j < 8; ++j) acc[i][j] = fmaf(xv[i], dv[j], acc[i][j]);
    }
#pragma unroll
    for (int i = 0; i < 8; ++i)
#pragma unroll
      for (int j = 0; j < 2; ++j)
        *reinterpret_cast<float4*>(
            &HB[(size_t)(n0 + nl + i) * NATOM + k0 + kl + j * 4]) =
            *reinterpret_cast<float4*>(&acc[i][j * 4]);
  }
}

// ---------------------------------------------------------------------------
// DPP wave64 reductions (VALU latency, no LDS): row_shr 1/2/4/8 then
// row_bcast15/31 leaves the full reduce in lane 63; readlane broadcasts.
// old = x with bound_ctrl=false -> invalid lanes keep x (neutral element).
// HW-verified correct in round 6.
// ---------------------------------------------------------------------------
template <int CTRL>
__device__ __forceinline__ float dpp_fmax(float x) {
  int s = __builtin_amdgcn_update_dpp(__float_as_int(x), __float_as_int(x),
                                      CTRL, 0xf, 0xf, false);
  return fmaxf(x, __int_as_float(s));
}
template <int CTRL>
__device__ __forceinline__ unsigned dpp_umin(unsigned x) {
  unsigned s = (unsigned)__builtin_amdgcn_update_dpp((int)x, (int)x, CTRL,
                                                     0xf, 0xf, false);
  return x < s ? x : s;
}
__device__ __forceinline__ float wave_max_bcast(float x) {
  x = dpp_fmax<0x111>(x);  // row_shr:1
  x = dpp_fmax<0x112>(x);  // row_shr:2
  x = dpp_fmax<0x114>(x);  // row_shr:4
  x = dpp_fmax<0x118>(x);  // row_shr:8
  x = dpp_fmax<0x142>(x);  // row_bcast:15
  x = dpp_fmax<0x143>(x);  // row_bcast:31
  return __int_as_float(__builtin_amdgcn_readlane(__float_as_int(x), 63));
}
__device__ __forceinline__ int wave_minu_bcast(unsigned x) {
  x = dpp_umin<0x111>(x);
  x = dpp_umin<0x112>(x);
  x = dpp_umin<0x114>(x);
  x = dpp_umin<0x118>(x);
  x = dpp_umin<0x142>(x);
  x = dpp_umin<0x143>(x);
  return __builtin_amdgcn_readlane((int)x, 63);
}

// ---------------------------------------------------------------------------
// Batched OMP: one 64-lane wave per pixel. Lane owns k = lane*16+j, j=0..15
// (consecutive atoms -> all G-row / HB traffic is dwordx4, 64B/lane).
// Argmax: exact f32 wave max via DPP, then wave-min index among score==M
// (first occurrence == np.argmax). hbs gather via readlane (bl is uniform).
// Selected G rows pinned in registers; diag from LDS-staged Gd.
// ---------------------------------------------------------------------------
template <bool HBWS, bool DTW>
__global__ __launch_bounds__(256, 2) void k_omp(const float* __restrict__ HB,
                                                const float* __restrict__ X,
                                                const float* __restrict__ D,
                                                const float* __restrict__ Dt,
                                                const float* __restrict__ G,
                                                const float* __restrict__ Gd,
                                                float* __restrict__ out) {
  const int lane = threadIdx.x & 63;
  const int lane16 = lane * 16;
  const int n =
      __builtin_amdgcn_readfirstlane(blockIdx.x * 4 + (threadIdx.x >> 6));

  // stage G diagonal (4 KB) into LDS once
  __shared__ float gdiag[NATOM];
  for (int i = threadIdx.x; i < NATOM; i += 256) gdiag[i] = Gd[i];
  __syncthreads();

  float hb[16];
  if (HBWS) {
#pragma unroll
    for (int q = 0; q < 4; ++q) {
      float4 v = *reinterpret_cast<const float4*>(
          &HB[(size_t)n * NATOM + lane16 + q * 4]);
      hb[q * 4 + 0] = v.x; hb[q * 4 + 1] = v.y;
      hb[q * 4 + 2] = v.z; hb[q * 4 + 3] = v.w;
    }
  } else {
    double a[16];
#pragma unroll
    for (int j = 0; j < 16; ++j) a[j] = 0.0;
    for (int d = 0; d < DIM; ++d) {
      float xd = X[(size_t)d * NPIX + n];
#pragma unroll
      for (int j = 0; j < 16; ++j)
        a[j] += (double)xd * (double)D[(size_t)d * NATOM + lane16 + j];
    }
#pragma unroll
    for (int j = 0; j < 16; ++j) hb[j] = (float)a[j];
  }
#pragma unroll
  for (int j = 0; j < 16; ++j) asm volatile("" : "+v"(hb[j]));

  unsigned mask = 0;  // bit j: atom (lane16+j) already selected
  int selI[SPAR];
  float rows[SPAR - 1][16];  // rows[i][j] = G[selI[i]][lane16+j]
  float Lm[SPAR][SPAR], invL[SPAR], ysel[SPAR], coefF[SPAR];

#pragma unroll 8
  for (int s = 0; s < SPAR; ++s) {
    // ---- scores ----
    float sc[16];
#pragma unroll
    for (int j = 0; j < 16; ++j) {
      float h = hb[j];
#pragma unroll
      for (int i = 0; i < SPAR - 1; ++i)
        if (i < s) h = fmaf(-coefF[i], rows[i][j], h);
      sc[j] = ((mask >> j) & 1u) ? -1.0f : fabsf(h);
    }
    // ---- wave max (exact f32, DPP) ----
    float m0 = fmaxf(fmaxf(fmaxf(sc[0], sc[1]), sc[2]), sc[3]);
    float m1 = fmaxf(fmaxf(fmaxf(sc[4], sc[5]), sc[6]), sc[7]);
    float m2 = fmaxf(fmaxf(fmaxf(sc[8], sc[9]), sc[10]), sc[11]);
    float m3 = fmaxf(fmaxf(fmaxf(sc[12], sc[13]), sc[14]), sc[15]);
    const float M = wave_max_bcast(fmaxf(fmaxf(m0, m1), fmaxf(m2, m3)));
    // ---- min index among score==M (first occurrence, as np.argmax) ----
    unsigned sel = NATOM;
#pragma unroll
    for (int j = 0; j < 16; ++j) {
      unsigned idx = (unsigned)(lane16 + j);
      unsigned cand = (sc[j] == M) ? idx : (unsigned)NATOM;
      sel = sel < cand ? sel : cand;
    }
    const int bk = wave_minu_bcast(sel);  // SGPR, wave-uniform
    selI[s] = bk;
    const int bl = bk >> 4, bj = bk & 15;
    if (lane == bl) mask |= (1u << bj);

    // gather h_bar[bk]: lane bl holds it in hb[bj]; bl is uniform -> readlane
    float v = 0.f;
#pragma unroll
    for (int j = 0; j < 16; ++j)
      if (j == bj) v = hb[j];
    const float hbs =
        __int_as_float(__builtin_amdgcn_readlane(__float_as_int(v), bl));

    // issue new-row fetch (dwordx4 x4); completes during chol/solve below
    if (s < SPAR - 1) {
#pragma unroll
      for (int q = 0; q < 4; ++q) {
        float4 rv = *reinterpret_cast<const float4*>(
            &G[(size_t)bk * NATOM + lane16 + q * 4]);
        rows[s][q * 4 + 0] = rv.x; rows[s][q * 4 + 1] = rv.y;
        rows[s][q * 4 + 2] = rv.z; rows[s][q * 4 + 3] = rv.w;
      }
    }

    // ---- Cholesky update: L_{s+1} = [[L, 0], [w^T, corner]] ----
    const float diag = gdiag[bk];  // uniform LDS broadcast
    float w[SPAR];
    float sq = 0.f;
#pragma unroll
    for (int i = 0; i < SPAR; ++i)
      if (i < s) {
        float a = G[(size_t)selI[i] * NATOM + bk];  // uniform (scalar) load
#pragma unroll
        for (int t = 0; t < SPAR; ++t)
          if (t < i) a = fmaf(-Lm[i][t], w[t], a);
        w[i] = a * invL[i];
        sq += w[i] * w[i];
        Lm[s][i] = w[i];
      }
    float cc = diag - sq;
    if (cc < 1e-6f) cc = 1e-6f;  // jnp.clip(..., CHOL_EPS)
    Lm[s][s] = sqrtf(cc);
    invL[s] = 1.0f / Lm[s][s];

    // ---- y_s (incremental forward solve) ----
    {
      float a = hbs;
#pragma unroll
      for (int t = 0; t < SPAR; ++t)
        if (t < s) a = fmaf(-Lm[s][t], ysel[t], a);
      ysel[s] = a * invL[s];
    }
    // ---- coef: backward solve L^T x = y ----
#pragma unroll
    for (int i = SPAR - 1; i >= 0; --i)
      if (i <= s) {
        float a = ysel[i];
#pragma unroll
        for (int t = 0; t < SPAR; ++t)
          if (t > i && t <= s) a = fmaf(-Lm[t][i], coefF[t], a);
        coefF[i] = a * invL[i];
      }

    // pin the fetched row: forces residency; waitcnt lands here (post-solve)
    if (s < SPAR - 1) {
#pragma unroll
      for (int j = 0; j < 16; ++j) asm volatile("" : "+v"(rows[s][j]));
    }
  }

  // ---- outputs: recon [n][64], I [n][8], coeffs [n][8] ----
  double r = 0.0;
#pragma unroll
  for (int i = 0; i < SPAR; ++i) {
    float dv = DTW ? Dt[(size_t)selI[i] * DIM + lane]
                   : D[(size_t)lane * NATOM + selI[i]];
    r += (double)coefF[i] * (double)dv;
  }
  out[(size_t)n * DIM + lane] = (float)r;

  float fi = 0.f, fc = 0.f;
#pragma unroll
  for (int i = 0; i < SPAR; ++i)
    if (lane == i) { fi = (float)selI[i]; fc = coefF[i]; }
  if (lane < SPAR) {
    out[(size_t)NPIX * DIM + (size_t)n * SPAR + lane] = fi;
    out[(size_t)NPIX * DIM + (size_t)NPIX * SPAR + (size_t)n * SPAR + lane] = fc;
  }
}

// Standalone gram for the tiny-workspace fallback
__global__ __launch_bounds__(256) void k_gram(const float* __restrict__ D,
                                              float* __restrict__ G,
                                              float* __restrict__ Gd) {
  int k1 = blockIdx.x;
  __shared__ float d1[DIM];
  if (threadIdx.x < DIM) d1[threadIdx.x] = D[(size_t)threadIdx.x * NATOM + k1];
  __syncthreads();
  for (int k2 = threadIdx.x; k2 < NATOM; k2 += 256) {
    double acc = 0.0;
#pragma unroll
    for (int d = 0; d < DIM; ++d)
      acc += (double)d1[d] * (double)D[(size_t)d * NATOM + k2];
    float g = (float)acc;
    if (k2 == k1) {
      g += 1e-4f;
      Gd[k1] = g;
    }
    G[(size_t)k1 * NATOM + k2] = g;
  }
}

extern "C" void kernel_launch(void* const* d_in, const int* in_sizes, int n_in,
                              void* d_out, int out_size, void* d_ws,
                              size_t ws_size, hipStream_t stream) {
  const float* X = (const float*)d_in[0];  // [64, 16384]
  const float* D = (const float*)d_in[1];  // [64, 1024]
  float* out = (float*)d_out;              // [recon | I | coeffs] as fp32
  float* G = (float*)d_ws;                 // 4 MB
  float* Dt = G + (size_t)NATOM * NATOM;   // 256 KB
  float* Gd = Dt + (size_t)NATOM * DIM;    // 4 KB
  float* HB = Gd + NATOM;                  // 64 MB
  const size_t needFull =
      ((size_t)NATOM * NATOM + (size_t)NATOM * DIM + NATOM +
       (size_t)NPIX * NATOM) * sizeof(float);

  if (ws_size >= needFull) {
    k_pre<<<dim3(2 * NATOM), dim3(256), 0, stream>>>(X, D, G, Dt, Gd, HB);
    k_omp<true, true><<<dim3(NPIX / 4), dim3(256), 0, stream>>>(
        HB, X, D, Dt, G, Gd, out);
  } else {
    k_gram<<<dim3(NATOM), dim3(256), 0, stream>>>(D, G, Gd);
    k_omp<false, false><<<dim3(NPIX / 4), dim3(256), 0, stream>>>(
        nullptr, X, D, nullptr, G, Gd, out);
  }
}

// Round 8
// 124.996 us; speedup vs baseline: 2.5837x; 1.0777x over previous
//
#include <hip/hip_runtime.h>
#include <cmath>

#define NPIX 16384
#define NATOM 1024
#define DIM 64
#define SPAR 8

// ---------------------------------------------------------------------------
// Fused pre-pass, grid-partitioned:
//   blocks [0, 1024):    G row k1 = D^T D + 1e-4 I (fp64 acc); Dt row; Gd[k1]
//   blocks [1024, 2048): HB 128n x 128k tile (fp32, 8x8/thread)
// ---------------------------------------------------------------------------
__global__ __launch_bounds__(256) void k_pre(const float* __restrict__ X,
                                             const float* __restrict__ D,
                                             float* __restrict__ G,
                                             float* __restrict__ Dt,
                                             float* __restrict__ Gd,
                                             float* __restrict__ HB) {
  __shared__ float smem[2 * DIM * 128];  // 64 KiB
  if (blockIdx.x < NATOM) {
    const int k1 = blockIdx.x;
    float* d1 = smem;
    if (threadIdx.x < DIM) {
      float v = D[(size_t)threadIdx.x * NATOM + k1];
      d1[threadIdx.x] = v;
      Dt[(size_t)k1 * DIM + threadIdx.x] = v;  // transpose for recon gather
    }
    __syncthreads();
    for (int k2 = threadIdx.x; k2 < NATOM; k2 += 256) {
      double acc = 0.0;
#pragma unroll
      for (int d = 0; d < DIM; ++d)
        acc += (double)d1[d] * (double)D[(size_t)d * NATOM + k2];
      float g = (float)acc;
      if (k2 == k1) {
        g += 1e-4f;
        Gd[k1] = g;
      }
      G[(size_t)k1 * NATOM + k2] = g;
    }
  } else {
    const int bx = blockIdx.x - NATOM;
    const int n0 = (bx & 127) * 128, k0 = (bx >> 7) * 128;
    float(*sX)[128] = (float(*)[128])smem;
    float(*sD)[128] = (float(*)[128])(smem + DIM * 128);
    for (int i = threadIdx.x; i < DIM * 32; i += 256) {
      int d = i >> 5, c4 = (i & 31) * 4;
      *reinterpret_cast<float4*>(&sX[d][c4]) =
          *reinterpret_cast<const float4*>(&X[(size_t)d * NPIX + n0 + c4]);
      *reinterpret_cast<float4*>(&sD[d][c4]) =
          *reinterpret_cast<const float4*>(&D[(size_t)d * NATOM + k0 + c4]);
    }
    __syncthreads();
    const int nl = (threadIdx.x & 15) * 8;
    const int kl = (threadIdx.x >> 4) * 8;
    float acc[8][8];
#pragma unroll
    for (int i = 0; i < 8; ++i)
#pragma unroll
      for (int j = 0; j < 8; ++j) acc[i][j] = 0.f;
#pragma unroll 4
    for (int d = 0; d < DIM; ++d) {
      float xv[8], dv[8];
      *reinterpret_cast<float4*>(&xv[0]) = *reinterpret_cast<float4*>(&sX[d][nl]);
      *reinterpret_cast<float4*>(&xv[4]) = *reinterpret_cast<float4*>(&sX[d][nl + 4]);
      *reinterpret_cast<float4*>(&dv[0]) = *reinterpret_cast<float4*>(&sD[d][kl]);
      *reinterpret_cast<float4*>(&dv[4]) = *reinterpret_cast<float4*>(&sD[d][kl + 4]);
#pragma unroll
      for (int i = 0; i < 8; ++i)
#pragma unroll
        for (int j = 0; j < 8; ++j) acc[i][j] = fmaf(xv[i], dv[j], acc[i][j]);
    }
#pragma unroll
    for (int i = 0; i < 8; ++i)
#pragma unroll
      for (int j = 0; j < 2; ++j)
        *reinterpret_cast<float4*>(
            &HB[(size_t)(n0 + nl + i) * NATOM + k0 + kl + j * 4]) =
            *reinterpret_cast<float4*>(&acc[i][j * 4]);
  }
}

// ---------------------------------------------------------------------------
// DPP wave64 reductions (VALU latency, no LDS). HW-verified (rounds 6/7).
// ---------------------------------------------------------------------------
template <int CTRL>
__device__ __forceinline__ float dpp_fmax(float x) {
  int s = __builtin_amdgcn_update_dpp(__float_as_int(x), __float_as_int(x),
                                      CTRL, 0xf, 0xf, false);
  return fmaxf(x, __int_as_float(s));
}
template <int CTRL>
__device__ __forceinline__ unsigned dpp_umin(unsigned x) {
  unsigned s = (unsigned)__builtin_amdgcn_update_dpp((int)x, (int)x, CTRL,
                                                     0xf, 0xf, false);
  return x < s ? x : s;
}
__device__ __forceinline__ float wave_max_bcast(float x) {
  x = dpp_fmax<0x111>(x);  // row_shr:1
  x = dpp_fmax<0x112>(x);  // row_shr:2
  x = dpp_fmax<0x114>(x);  // row_shr:4
  x = dpp_fmax<0x118>(x);  // row_shr:8
  x = dpp_fmax<0x142>(x);  // row_bcast:15
  x = dpp_fmax<0x143>(x);  // row_bcast:31
  return __int_as_float(__builtin_amdgcn_readlane(__float_as_int(x), 63));
}
__device__ __forceinline__ int wave_minu_bcast(unsigned x) {
  x = dpp_umin<0x111>(x);
  x = dpp_umin<0x112>(x);
  x = dpp_umin<0x114>(x);
  x = dpp_umin<0x118>(x);
  x = dpp_umin<0x142>(x);
  x = dpp_umin<0x143>(x);
  return __builtin_amdgcn_readlane((int)x, 63);
}

// ---------------------------------------------------------------------------
// Batched OMP: ONE WAVE PER PIXEL, 64-thread blocks (no LDS, no barriers).
// Lane owns atoms k = lane*16+j, j=0..15 (dwordx4-coalesced G/HB traffic).
// Masking: selected atom's hb entry is poisoned to NaN — NaN propagates
// through the beta FMAs/fabs, loses every fmaxf (IEEE maxnum ignores NaN)
// and fails sc==M, reproducing the -1.0-mask selection exactly.
// Argmax: exact f32 wave max via DPP, then wave-min index among sc==M
// (first occurrence == np.argmax). diag via wave-uniform scalar load of Gd.
// Selected G rows pinned in registers (vmcnt lands post-solve).
// ---------------------------------------------------------------------------
template <bool HBWS, bool DTW>
__global__ __launch_bounds__(64) void k_omp(const float* __restrict__ HB,
                                            const float* __restrict__ X,
                                            const float* __restrict__ D,
                                            const float* __restrict__ Dt,
                                            const float* __restrict__ G,
                                            const float* __restrict__ Gd,
                                            float* __restrict__ out) {
  const int lane = threadIdx.x & 63;
  const int lane16 = lane * 16;
  const int n = __builtin_amdgcn_readfirstlane(blockIdx.x);

  float hb[16];
  if (HBWS) {
#pragma unroll
    for (int q = 0; q < 4; ++q) {
      float4 v = *reinterpret_cast<const float4*>(
          &HB[(size_t)n * NATOM + lane16 + q * 4]);
      hb[q * 4 + 0] = v.x; hb[q * 4 + 1] = v.y;
      hb[q * 4 + 2] = v.z; hb[q * 4 + 3] = v.w;
    }
  } else {
    double a[16];
#pragma unroll
    for (int j = 0; j < 16; ++j) a[j] = 0.0;
    for (int d = 0; d < DIM; ++d) {
      float xd = X[(size_t)d * NPIX + n];
#pragma unroll
      for (int j = 0; j < 16; ++j)
        a[j] += (double)xd * (double)D[(size_t)d * NATOM + lane16 + j];
    }
#pragma unroll
    for (int j = 0; j < 16; ++j) hb[j] = (float)a[j];
  }
#pragma unroll
  for (int j = 0; j < 16; ++j) asm volatile("" : "+v"(hb[j]));

  int selI[SPAR];
  float rows[SPAR - 1][16];  // rows[i][j] = G[selI[i]][lane16+j]
  float Lm[SPAR][SPAR], invL[SPAR], ysel[SPAR], coefF[SPAR];

#pragma unroll 8
  for (int s = 0; s < SPAR; ++s) {
    // ---- scores: sc = |hb - sum_i coef_i * rows_i| (NaN where selected) ----
    float sc[16];
#pragma unroll
    for (int j = 0; j < 16; ++j) {
      float h = hb[j];
#pragma unroll
      for (int i = 0; i < SPAR - 1; ++i)
        if (i < s) h = fmaf(-coefF[i], rows[i][j], h);
      sc[j] = fabsf(h);
    }
    // ---- wave max (exact f32, DPP; fmaxf ignores NaN) ----
    float m0 = fmaxf(fmaxf(fmaxf(sc[0], sc[1]), sc[2]), sc[3]);
    float m1 = fmaxf(fmaxf(fmaxf(sc[4], sc[5]), sc[6]), sc[7]);
    float m2 = fmaxf(fmaxf(fmaxf(sc[8], sc[9]), sc[10]), sc[11]);
    float m3 = fmaxf(fmaxf(fmaxf(sc[12], sc[13]), sc[14]), sc[15]);
    const float M = wave_max_bcast(fmaxf(fmaxf(m0, m1), fmaxf(m2, m3)));
    // ---- min index among sc==M (first occurrence, as np.argmax) ----
    unsigned sel = NATOM;
#pragma unroll
    for (int j = 0; j < 16; ++j) {
      unsigned idx = (unsigned)(lane16 + j);
      unsigned cand = (sc[j] == M) ? idx : (unsigned)NATOM;
      sel = sel < cand ? sel : cand;
    }
    const int bk = wave_minu_bcast(sel);  // SGPR, wave-uniform
    selI[s] = bk;
    const int bl = bk >> 4, bj = bk & 15;

    // gather h_bar[bk]: lane bl holds it in hb[bj]; bl uniform -> readlane
    float v = 0.f;
#pragma unroll
    for (int j = 0; j < 16; ++j)
      if (j == bj) v = hb[j];
    const float hbs =
        __int_as_float(__builtin_amdgcn_readlane(__float_as_int(v), bl));

    // poison the selected slot: it loses every future argmax (NaN semantics)
#pragma unroll
    for (int j = 0; j < 16; ++j)
      if (j == bj && lane == bl) hb[j] = __builtin_nanf("");

    // issue new-row fetch (dwordx4 x4); completes during chol/solve below
    if (s < SPAR - 1) {
#pragma unroll
      for (int q = 0; q < 4; ++q) {
        float4 rv = *reinterpret_cast<const float4*>(
            &G[(size_t)bk * NATOM + lane16 + q * 4]);
        rows[s][q * 4 + 0] = rv.x; rows[s][q * 4 + 1] = rv.y;
        rows[s][q * 4 + 2] = rv.z; rows[s][q * 4 + 3] = rv.w;
      }
    }

    // ---- Cholesky update: L_{s+1} = [[L, 0], [w^T, corner]] ----
    const float diag = Gd[bk];  // wave-uniform scalar load, issued early
    float w[SPAR];
    float sq = 0.f;
#pragma unroll
    for (int i = 0; i < SPAR; ++i)
      if (i < s) {
        float a = G[(size_t)selI[i] * NATOM + bk];  // uniform (scalar) load
#pragma unroll
        for (int t = 0; t < SPAR; ++t)
          if (t < i) a = fmaf(-Lm[i][t], w[t], a);
        w[i] = a * invL[i];
        sq += w[i] * w[i];
        Lm[s][i] = w[i];
      }
    float cc = diag - sq;
    if (cc < 1e-6f) cc = 1e-6f;  // jnp.clip(..., CHOL_EPS)
    invL[s] = 1.0f / sqrtf(cc);  // Lm diag never stored (only invL is read)

    // ---- y_s (incremental forward solve) ----
    {
      float a = hbs;
#pragma unroll
      for (int t = 0; t < SPAR; ++t)
        if (t < s) a = fmaf(-Lm[s][t], ysel[t], a);
      ysel[s] = a * invL[s];
    }
    // ---- coef: backward solve L^T x = y ----
#pragma unroll
    for (int i = SPAR - 1; i >= 0; --i)
      if (i <= s) {
        float a = ysel[i];
#pragma unroll
        for (int t = 0; t < SPAR; ++t)
          if (t > i && t <= s) a = fmaf(-Lm[t][i], coefF[t], a);
        coefF[i] = a * invL[i];
      }

    // pin the fetched row: forces residency; waitcnt lands here (post-solve)
    if (s < SPAR - 1) {
#pragma unroll
      for (int j = 0; j < 16; ++j) asm volatile("" : "+v"(rows[s][j]));
    }
  }

  // ---- outputs: recon [n][64], I [n][8], coeffs [n][8] ----
  double r = 0.0;
#pragma unroll
  for (int i = 0; i < SPAR; ++i) {
    float dv = DTW ? Dt[(size_t)selI[i] * DIM + lane]
                   : D[(size_t)lane * NATOM + selI[i]];
    r += (double)coefF[i] * (double)dv;
  }
  out[(size_t)n * DIM + lane] = (float)r;

  float fi = 0.f, fc = 0.f;
#pragma unroll
  for (int i = 0; i < SPAR; ++i)
    if (lane == i) { fi = (float)selI[i]; fc = coefF[i]; }
  if (lane < SPAR) {
    out[(size_t)NPIX * DIM + (size_t)n * SPAR + lane] = fi;
    out[(size_t)NPIX * DIM + (size_t)NPIX * SPAR + (size_t)n * SPAR + lane] = fc;
  }
}

// Standalone gram for the tiny-workspace fallback
__global__ __launch_bounds__(256) void k_gram(const float* __restrict__ D,
                                              float* __restrict__ G,
                                              float* __restrict__ Gd) {
  int k1 = blockIdx.x;
  __shared__ float d1[DIM];
  if (threadIdx.x < DIM) d1[threadIdx.x] = D[(size_t)threadIdx.x * NATOM + k1];
  __syncthreads();
  for (int k2 = threadIdx.x; k2 < NATOM; k2 += 256) {
    double acc = 0.0;
#pragma unroll
    for (int d = 0; d < DIM; ++d)
      acc += (double)d1[d] * (double)D[(size_t)d * NATOM + k2];
    float g = (float)acc;
    if (k2 == k1) {
      g += 1e-4f;
      Gd[k1] = g;
    }
    G[(size_t)k1 * NATOM + k2] = g;
  }
}

extern "C" void kernel_launch(void* const* d_in, const int* in_sizes, int n_in,
                              void* d_out, int out_size, void* d_ws,
                              size_t ws_size, hipStream_t stream) {
  const float* X = (const float*)d_in[0];  // [64, 16384]
  const float* D = (const float*)d_in[1];  // [64, 1024]
  float* out = (float*)d_out;              // [recon | I | coeffs] as fp32
  float* G = (float*)d_ws;                 // 4 MB
  float* Dt = G + (size_t)NATOM * NATOM;   // 256 KB
  float* Gd = Dt + (size_t)NATOM * DIM;    // 4 KB
  float* HB = Gd + NATOM;                  // 64 MB
  const size_t needFull =
      ((size_t)NATOM * NATOM + (size_t)NATOM * DIM + NATOM +
       (size_t)NPIX * NATOM) * sizeof(float);

  if (ws_size >= needFull) {
    k_pre<<<dim3(2 * NATOM), dim3(256), 0, stream>>>(X, D, G, Dt, Gd, HB);
    k_omp<true, true><<<dim3(NPIX), dim3(64), 0, stream>>>(
        HB, X, D, Dt, G, Gd, out);
  } else {
    k_gram<<<dim3(NATOM), dim3(256), 0, stream>>>(D, G, Gd);
    k_omp<false, false><<<dim3(NPIX), dim3(64), 0, stream>>>(
        nullptr, X, D, nullptr, G, Gd, out);
  }
}